// Round 3
// baseline (578.006 us; speedup 1.0000x reference)
//
#include <hip/hip_runtime.h>
#include <hip/hip_bf16.h>

#define B_SZ 128
#define IC   1024
#define KD   256
#define NC   16
#define DC   32
#define NN   512
#define EPSQ 1e-7f

// ---- ubar[b,k] = sum_i u[b,i,k] ----
__global__ void reduce_u_k(const float* __restrict__ u, float* __restrict__ ubar) {
    int bid = blockIdx.x;            // 1024 = 128 b * 8 slices
    int b   = bid >> 3;
    int i0  = (bid & 7) << 7;
    int k   = threadIdx.x;           // 256 k columns
    const float* p = u + ((size_t)b * IC + i0) * KD + k;
    float acc = 0.f;
    #pragma unroll 8
    for (int i = 0; i < 128; ++i) acc += p[(size_t)i * KD];
    atomicAdd(&ubar[b * KD + k], acc);
}

// ---- v0 = squash((ubar @ W)/16) : iteration 0 (uniform softmax shortcut) ----
__global__ void v0_k(const float* __restrict__ ubar, const float* __restrict__ W,
                     float* __restrict__ v) {
    __shared__ float ub[KD];
    int b = blockIdx.x, t = threadIdx.x;
    ub[t] = ubar[b * KD + t];
    __syncthreads();
    int n  = t >> 4;
    int d0 = (t & 15) * 2;
    float s0 = 0.f, s1 = 0.f;
    #pragma unroll 4
    for (int k = 0; k < KD; ++k) {
        float2 w = *(const float2*)&W[(size_t)k * NN + n * DC + d0];
        float uu = ub[k];
        s0 = fmaf(uu, w.x, s0);
        s1 = fmaf(uu, w.y, s1);
    }
    s0 *= 0.0625f; s1 *= 0.0625f;
    float ss = s0 * s0 + s1 * s1;
    ss += __shfl_xor(ss, 1);
    ss += __shfl_xor(ss, 2);
    ss += __shfl_xor(ss, 4);
    ss += __shfl_xor(ss, 8);
    float inv = 1.f / sqrtf(ss + EPSQ);
    float2 o = {s0 * inv, s1 * inv};
    *(float2*)&v[b * NN + n * DC + d0] = o;
}

// ---- wv[b,n,k] = sum_d W[k, n*32+d] * v[b,n,d] ----
__global__ void wv_k(const float* __restrict__ W, const float* __restrict__ v,
                     float* __restrict__ wv) {
    __shared__ float vl[NN];
    int b = blockIdx.x, t = threadIdx.x;
    vl[t] = v[b * NN + t];
    vl[t + 256] = v[b * NN + t + 256];
    __syncthreads();
    int k = t;                        // one W row per thread (L2-resident W)
    #pragma unroll
    for (int n = 0; n < NC; ++n) {
        float acc = 0.f;
        #pragma unroll
        for (int d = 0; d < DC; d += 4) {
            float4 w = *(const float4*)&W[(size_t)k * NN + n * DC + d];
            acc = fmaf(w.x, vl[n * DC + d],     acc);
            acc = fmaf(w.y, vl[n * DC + d + 1], acc);
            acc = fmaf(w.z, vl[n * DC + d + 2], acc);
            acc = fmaf(w.w, vl[n * DC + d + 3], acc);
        }
        wv[((size_t)b * NC + n) * KD + k] = acc;  // coalesced over k
    }
}

// ---- fused routing pass: logits -> softmax -> cu += c^T u (per b) ----
// grid 1024 = 128 b * 8 chunks(128 rows); 256 threads; 4 sub-chunks of 32 rows
__global__ __launch_bounds__(256)
void fused_route_k(const float* __restrict__ u, const float* __restrict__ wv,
                   float* __restrict__ cu) {
    __shared__ float ul[32][260];     // pad 260: p1 reads conflict-free, 16B-aligned
    __shared__ float wvl[NC][260];
    __shared__ float cl[32][NC];

    const int b   = blockIdx.x >> 3;
    const int ch  = blockIdx.x & 7;
    const int t   = threadIdx.x;

    // load wv[b] once
    for (int j = 0; j < 16; ++j) {
        int idx = j * 256 + t;
        wvl[idx >> 8][idx & 255] = wv[(size_t)b * NC * KD + idx];
    }

    // phase-2 register accumulators: thread owns (n=nh, n=nh+8) x 8 k
    const int nh = t & 7;
    const int kb = t >> 3;            // 0..31, k-slice [8*kb, 8*kb+8)
    float a0[8], a1[8];
    #pragma unroll
    for (int j = 0; j < 8; ++j) { a0[j] = 0.f; a1[j] = 0.f; }

    const int r1 = t >> 3;            // phase-1 row 0..31
    const int ng = t & 7;             // phase-1 capsules ng, ng+8
    __syncthreads();

    for (int c4 = 0; c4 < 4; ++c4) {
        const int i0 = (ch << 7) + (c4 << 5);
        // stage 32 rows, coalesced float4
        #pragma unroll
        for (int j = 0; j < 8; ++j) {
            int idx = j * 256 + t;            // float4 index
            int r = idx >> 6, kq = idx & 63;
            float4 val = *(const float4*)&u[((size_t)b * IC + i0 + r) * KD + kq * 4];
            *(float4*)&ul[r][kq * 4] = val;
        }
        __syncthreads();

        // phase 1: logits for row r1, capsules ng/ng+8
        float l0 = 0.f, l1 = 0.f;
        #pragma unroll 8
        for (int k = 0; k < KD; k += 4) {
            float4 uq = *(const float4*)&ul[r1][k];
            float4 w0 = *(const float4*)&wvl[ng][k];
            float4 w1 = *(const float4*)&wvl[ng + 8][k];
            l0 = fmaf(uq.x, w0.x, fmaf(uq.y, w0.y, fmaf(uq.z, w0.z, fmaf(uq.w, w0.w, l0))));
            l1 = fmaf(uq.x, w1.x, fmaf(uq.y, w1.y, fmaf(uq.z, w1.z, fmaf(uq.w, w1.w, l1))));
        }
        // softmax over 16 capsules: reduce across the row's 8 lanes (bits 0..2)
        float m = fmaxf(l0, l1);
        m = fmaxf(m, __shfl_xor(m, 1));
        m = fmaxf(m, __shfl_xor(m, 2));
        m = fmaxf(m, __shfl_xor(m, 4));
        float e0 = __expf(l0 - m), e1 = __expf(l1 - m);
        float se = e0 + e1;
        se += __shfl_xor(se, 1);
        se += __shfl_xor(se, 2);
        se += __shfl_xor(se, 4);
        float inv = 1.f / se;
        cl[r1][ng]     = e0 * inv;
        cl[r1][ng + 8] = e1 * inv;
        __syncthreads();

        // phase 2: cu[n, kslice] += c[r,n] * u[r, kslice]
        #pragma unroll 4
        for (int r = 0; r < 32; ++r) {
            float c0 = cl[r][nh];
            float c1 = cl[r][nh + 8];
            float4 u0 = *(const float4*)&ul[r][kb * 8];
            float4 u1 = *(const float4*)&ul[r][kb * 8 + 4];
            a0[0] = fmaf(c0, u0.x, a0[0]); a0[1] = fmaf(c0, u0.y, a0[1]);
            a0[2] = fmaf(c0, u0.z, a0[2]); a0[3] = fmaf(c0, u0.w, a0[3]);
            a0[4] = fmaf(c0, u1.x, a0[4]); a0[5] = fmaf(c0, u1.y, a0[5]);
            a0[6] = fmaf(c0, u1.z, a0[6]); a0[7] = fmaf(c0, u1.w, a0[7]);
            a1[0] = fmaf(c1, u0.x, a1[0]); a1[1] = fmaf(c1, u0.y, a1[1]);
            a1[2] = fmaf(c1, u0.z, a1[2]); a1[3] = fmaf(c1, u0.w, a1[3]);
            a1[4] = fmaf(c1, u1.x, a1[4]); a1[5] = fmaf(c1, u1.y, a1[5]);
            a1[6] = fmaf(c1, u1.z, a1[6]); a1[7] = fmaf(c1, u1.w, a1[7]);
        }
        __syncthreads();
    }

    float* cup = cu + (size_t)b * NC * KD;
    #pragma unroll
    for (int j = 0; j < 8; ++j) {
        atomicAdd(&cup[nh * KD + kb * 8 + j],       a0[j]);
        atomicAdd(&cup[(nh + 8) * KD + kb * 8 + j], a1[j]);
    }
}

// ---- s[b,n,d] = cu[b,n,:] @ W[:, n*32+d]; out = squash(s) ----
__global__ void sv_k(const float* __restrict__ cu, const float* __restrict__ W,
                     float* __restrict__ out) {
    __shared__ float cul[NC * 258];
    int b = blockIdx.x, t = threadIdx.x;
    for (int j = 0; j < 16; ++j) {
        int idx = j * 256 + t;
        cul[(idx >> 8) * 258 + (idx & 255)] = cu[(size_t)b * NC * KD + idx];
    }
    __syncthreads();
    int n  = t >> 4;
    int d0 = (t & 15) * 2;
    float s0 = 0.f, s1 = 0.f;
    #pragma unroll 4
    for (int k = 0; k < KD; ++k) {
        float2 w = *(const float2*)&W[(size_t)k * NN + n * DC + d0];
        float cc = cul[n * 258 + k];
        s0 = fmaf(cc, w.x, s0);
        s1 = fmaf(cc, w.y, s1);
    }
    float ss = s0 * s0 + s1 * s1;
    ss += __shfl_xor(ss, 1);
    ss += __shfl_xor(ss, 2);
    ss += __shfl_xor(ss, 4);
    ss += __shfl_xor(ss, 8);
    float inv = 1.f / sqrtf(ss + EPSQ);
    float2 o = {s0 * inv, s1 * inv};
    *(float2*)&out[b * NN + n * DC + d0] = o;
}

extern "C" void kernel_launch(void* const* d_in, const int* in_sizes, int n_in,
                              void* d_out, int out_size, void* d_ws, size_t ws_size,
                              hipStream_t stream) {
    (void)in_sizes; (void)n_in; (void)out_size; (void)ws_size;
    const float* u = (const float*)d_in[0];
    const float* W = (const float*)d_in[1];

    float* ubar = (float*)d_ws;                       // 128*256
    float* v    = ubar + B_SZ * KD;                   // 128*512
    float* wv   = v + B_SZ * NN;                      // 128*16*256
    float* cu   = wv + (size_t)B_SZ * NC * KD;        // 128*16*256  (~4.6 MB total)

    hipMemsetAsync(ubar, 0, B_SZ * KD * sizeof(float), stream);
    reduce_u_k<<<1024, 256, 0, stream>>>(u, ubar);
    v0_k<<<B_SZ, 256, 0, stream>>>(ubar, W, v);

    // routing pass 1
    wv_k<<<B_SZ, 256, 0, stream>>>(W, v, wv);
    hipMemsetAsync(cu, 0, (size_t)B_SZ * NC * KD * sizeof(float), stream);
    fused_route_k<<<1024, 256, 0, stream>>>(u, wv, cu);
    sv_k<<<B_SZ, 256, 0, stream>>>(cu, W, v);

    // routing pass 2 (final)
    wv_k<<<B_SZ, 256, 0, stream>>>(W, v, wv);
    hipMemsetAsync(cu, 0, (size_t)B_SZ * NC * KD * sizeof(float), stream);
    fused_route_k<<<1024, 256, 0, stream>>>(u, wv, cu);
    sv_k<<<B_SZ, 256, 0, stream>>>(cu, W, (float*)d_out);
}

// Round 4
// 443.812 us; speedup vs baseline: 1.3024x; 1.3024x over previous
//
#include <hip/hip_runtime.h>
#include <hip/hip_bf16.h>

#define B_SZ 128
#define IC   1024
#define KD   256
#define NC   16
#define DC   32
#define NN   512
#define NCH  8
#define EPSQ 1e-7f

// ---- async global->LDS 16B helper (linear dest, per-lane source) ----
__device__ __forceinline__ void gload_lds16(const float* g, float* l) {
    __builtin_amdgcn_global_load_lds(
        (const __attribute__((address_space(1))) unsigned int*)g,
        (__attribute__((address_space(3))) unsigned int*)l, 16, 0, 0);
}

// ---- ubar_part[b][ch][k] = sum of 128 rows ----
__global__ __launch_bounds__(256)
void reduce_u_k(const float* __restrict__ u, float* __restrict__ ubar_part) {
    const int bid = blockIdx.x;          // 1024 = b*8 + ch
    const int b = bid >> 3, ch = bid & 7;
    const int t = threadIdx.x;
    const int kq = t & 63;
    const int rh = t >> 6;
    const float* p = u + ((size_t)b * IC + ch * 128 + rh * 32) * KD + kq * 4;
    float4 a = {0.f, 0.f, 0.f, 0.f};
    #pragma unroll 8
    for (int r = 0; r < 32; ++r) {
        float4 x = *(const float4*)(p + (size_t)r * KD);
        a.x += x.x; a.y += x.y; a.z += x.z; a.w += x.w;
    }
    __shared__ float4 sp[4][64];
    sp[rh][kq] = a;
    __syncthreads();
    if (t < 64) {
        float4 s0 = sp[0][t], s1 = sp[1][t], s2 = sp[2][t], s3 = sp[3][t];
        float4 o = { s0.x + s1.x + s2.x + s3.x, s0.y + s1.y + s2.y + s3.y,
                     s0.z + s1.z + s2.z + s3.z, s0.w + s1.w + s2.w + s3.w };
        *(float4*)&ubar_part[(size_t)bid * KD + t * 4] = o;
    }
}

// ---- v0 = squash((ubar @ W)/16) ----
__global__ __launch_bounds__(256)
void v0_k(const float* __restrict__ ubar_part, const float* __restrict__ W,
          float* __restrict__ v) {
    const int bid = blockIdx.x;          // 512 = b*4 + q
    const int b = bid >> 2, q = bid & 3;
    const int t = threadIdx.x;
    __shared__ float ub[KD];
    __shared__ float ps[2][128];
    {
        float s = 0.f;
        #pragma unroll
        for (int ch = 0; ch < 8; ++ch)
            s += ubar_part[((size_t)b * NCH + ch) * KD + t];
        ub[t] = s;
    }
    __syncthreads();
    const int c   = t & 127;
    const int kh  = t >> 7;
    const int col = q * 128 + c;
    float s = 0.f;
    #pragma unroll 4
    for (int k = kh * 128; k < kh * 128 + 128; ++k)
        s = fmaf(ub[k], W[(size_t)k * NN + col], s);
    ps[kh][c] = s;
    __syncthreads();
    if (t < 128) {
        float sv = (ps[0][t] + ps[1][t]) * 0.0625f;
        float sq = sv * sv;
        sq += __shfl_xor(sq, 1);
        sq += __shfl_xor(sq, 2);
        sq += __shfl_xor(sq, 4);
        sq += __shfl_xor(sq, 8);
        sq += __shfl_xor(sq, 16);
        float inv = 1.f / sqrtf(sq + EPSQ);
        v[(size_t)b * NN + q * 128 + t] = sv * inv;
    }
}

// ---- wv[b][n][k] = sum_d W[k][n*32+d] * v[b][n*32+d] ----
__global__ __launch_bounds__(256)
void wv_k(const float* __restrict__ W, const float* __restrict__ v,
          float* __restrict__ wv) {
    const int bid = blockIdx.x;          // 512 = b*4 + kq
    const int b = bid >> 2, kq = bid & 3;
    const int t = threadIdx.x;
    __shared__ float vl[NN];
    vl[t]       = v[(size_t)b * NN + t];
    vl[t + 256] = v[(size_t)b * NN + t + 256];
    __syncthreads();
    const int kl = t & 63, ng = t >> 6;
    const int k = kq * 64 + kl;
    #pragma unroll
    for (int c = 0; c < 4; ++c) {
        const int cap = ng * 4 + c;
        float acc = 0.f;
        #pragma unroll
        for (int dq = 0; dq < 8; ++dq) {
            float4 w4 = *(const float4*)&W[(size_t)k * NN + cap * DC + dq * 4];
            acc = fmaf(w4.x, vl[cap * DC + dq * 4],     acc);
            acc = fmaf(w4.y, vl[cap * DC + dq * 4 + 1], acc);
            acc = fmaf(w4.z, vl[cap * DC + dq * 4 + 2], acc);
            acc = fmaf(w4.w, vl[cap * DC + dq * 4 + 3], acc);
        }
        wv[((size_t)b * NC + cap) * KD + k] = acc;
    }
}

// ---- fused routing pass over one 128-row chunk ----
// phase1: logits (8r x 4n x 16k tiles, wv in regs), butterfly over k-slices
// phase2: cu_part accumulation (4n x 4k per thread over 32 rows)
__global__ __launch_bounds__(256)
void fused_route_k(const float* __restrict__ u, const float* __restrict__ wv,
                   float* __restrict__ cu_part) {
    __shared__ float ul[32][KD];        // 32 KB; 16B-unit cols XORed by (row>>3)&3
    __shared__ float cT[NC][36];        // [cap][row], 36*4=144B row stride (16B-mult)

    const int bid  = blockIdx.x;        // 1024 = b*8 + ch
    const int b    = bid >> 3;
    const int ch   = bid & 7;
    const int t    = threadIdx.x;
    const int w    = t >> 6;            // wave = cap-group for phase1
    const int lane = t & 63;
    const int rt   = lane >> 4;         // row-tile (8 rows)
    const int ks   = lane & 15;         // k-slice (16 floats)
    const int nq   = t & 3;             // phase2 cap-quad
    const int kb   = t >> 2;            // phase2 float4 col 0..63

    // wv fragments in registers: caps w*4..+4, k in [ks*16, ks*16+16)
    float4 wvr[4][4];
    {
        const float* wp = wv + (size_t)b * NC * KD;
        #pragma unroll
        for (int c = 0; c < 4; ++c)
            #pragma unroll
            for (int j = 0; j < 4; ++j)
                wvr[c][j] = *(const float4*)(wp + (size_t)(w * 4 + c) * KD + ks * 16 + j * 4);
    }

    float acc2[4][4];
    #pragma unroll
    for (int c = 0; c < 4; ++c)
        #pragma unroll
        for (int j = 0; j < 4; ++j) acc2[c][j] = 0.f;

    const float* ub = u + ((size_t)b * IC + ch * 128) * KD;

    // prologue: stage subtile 0 (source pre-swizzled so LDS dest stays linear)
    #pragma unroll
    for (int j = 0; j < 8; ++j) {
        const int row = j * 4 + w;
        const int key = (row >> 3) & 3;
        gload_lds16(ub + (size_t)row * KD + ((lane ^ key) * 4), &ul[row][0]);
    }
    __syncthreads();

    for (int c4 = 0; c4 < 4; ++c4) {
        // ---- phase 1: partial logits ----
        float l[8][4];
        #pragma unroll
        for (int rr = 0; rr < 8; ++rr)
            #pragma unroll
            for (int c = 0; c < 4; ++c) l[rr][c] = 0.f;
        #pragma unroll
        for (int rr = 0; rr < 8; ++rr) {
            const int row = rt * 8 + rr;
            float4 uq[4];
            #pragma unroll
            for (int j = 0; j < 4; ++j)
                uq[j] = *(const float4*)&ul[row][((ks * 4 + j) ^ rt) * 4];
            #pragma unroll
            for (int c = 0; c < 4; ++c) {
                float s = l[rr][c];
                #pragma unroll
                for (int j = 0; j < 4; ++j) {
                    s = fmaf(uq[j].x, wvr[c][j].x, s);
                    s = fmaf(uq[j].y, wvr[c][j].y, s);
                    s = fmaf(uq[j].z, wvr[c][j].z, s);
                    s = fmaf(uq[j].w, wvr[c][j].w, s);
                }
                l[rr][c] = s;
            }
        }
        // butterfly-reduce over the 16 k-slices (lane bits 0..3)
        #pragma unroll
        for (int st = 1; st <= 8; st <<= 1)
            #pragma unroll
            for (int rr = 0; rr < 8; ++rr)
                #pragma unroll
                for (int c = 0; c < 4; ++c)
                    l[rr][c] += __shfl_xor(l[rr][c], st);
        // lanes ks<4 write cap w*4+ks for all 8 rows (static reg select)
        if (ks < 4) {
            #pragma unroll
            for (int rr = 0; rr < 8; ++rr) {
                float val = (ks == 0) ? l[rr][0] : (ks == 1) ? l[rr][1]
                          : (ks == 2) ? l[rr][2] : l[rr][3];
                cT[w * 4 + ks][rt * 8 + rr] = val;
            }
        }
        __syncthreads();

        // ---- softmax over the 16 capsules, per row ----
        {
            const int row = t >> 3;
            const int cg  = t & 7;
            float L0 = cT[cg][row];
            float L1 = cT[cg + 8][row];
            float m = fmaxf(L0, L1);
            m = fmaxf(m, __shfl_xor(m, 1));
            m = fmaxf(m, __shfl_xor(m, 2));
            m = fmaxf(m, __shfl_xor(m, 4));
            float e0 = __expf(L0 - m), e1 = __expf(L1 - m);
            float se = e0 + e1;
            se += __shfl_xor(se, 1);
            se += __shfl_xor(se, 2);
            se += __shfl_xor(se, 4);
            float inv = 1.f / se;
            cT[cg][row]     = e0 * inv;
            cT[cg + 8][row] = e1 * inv;
        }
        __syncthreads();

        // ---- phase 2: acc2[c][j] += c[cap][r] * u[r][kb*4+j] ----
        #pragma unroll
        for (int rb = 0; rb < 8; ++rb) {
            float4 cQ[4];
            #pragma unroll
            for (int c = 0; c < 4; ++c)
                cQ[c] = *(const float4*)&cT[nq * 4 + c][rb * 4];
            #pragma unroll
            for (int rr = 0; rr < 4; ++rr) {
                const int row = rb * 4 + rr;
                const int key = (row >> 3) & 3;
                float4 u4 = *(const float4*)&ul[row][((kb ^ key) * 4)];
                #pragma unroll
                for (int c = 0; c < 4; ++c) {
                    float cc = (rr == 0) ? cQ[c].x : (rr == 1) ? cQ[c].y
                             : (rr == 2) ? cQ[c].z : cQ[c].w;
                    acc2[c][0] = fmaf(cc, u4.x, acc2[c][0]);
                    acc2[c][1] = fmaf(cc, u4.y, acc2[c][1]);
                    acc2[c][2] = fmaf(cc, u4.z, acc2[c][2]);
                    acc2[c][3] = fmaf(cc, u4.w, acc2[c][3]);
                }
            }
        }
        __syncthreads();

        // ---- stage next subtile ----
        if (c4 < 3) {
            const float* ub2 = ub + (size_t)(c4 + 1) * 32 * KD;
            #pragma unroll
            for (int j = 0; j < 8; ++j) {
                const int row = j * 4 + w;
                const int key = (row >> 3) & 3;
                gload_lds16(ub2 + (size_t)row * KD + ((lane ^ key) * 4), &ul[row][0]);
            }
            __syncthreads();
        }
    }

    // ---- write partial cu (no atomics) ----
    float* cp = cu_part + ((size_t)b * NCH + ch) * NC * KD;
    #pragma unroll
    for (int c = 0; c < 4; ++c) {
        float4 o = {acc2[c][0], acc2[c][1], acc2[c][2], acc2[c][3]};
        *(float4*)(cp + (size_t)(nq * 4 + c) * KD + kb * 4) = o;
    }
}

// ---- s = (sum_ch cu_part) @ W block; out = squash(s) ----
__global__ __launch_bounds__(256)
void sv_k(const float* __restrict__ cu_part, const float* __restrict__ W,
          float* __restrict__ out) {
    const int bid = blockIdx.x;          // 512 = b*4 + q
    const int b = bid >> 2, q = bid & 3;
    const int t = threadIdx.x;
    __shared__ float cus[4][KD];
    __shared__ float ps[2][128];
    #pragma unroll
    for (int rep = 0; rep < 4; ++rep) {
        int idx = rep * 256 + t;
        int cl_ = idx >> 8;
        int k   = idx & 255;
        float s = 0.f;
        #pragma unroll
        for (int chh = 0; chh < 8; ++chh)
            s += cu_part[(((size_t)b * NCH + chh) * NC + q * 4 + cl_) * KD + k];
        cus[cl_][k] = s;
    }
    __syncthreads();
    const int c   = t & 127;
    const int kh  = t >> 7;
    const int col = q * 128 + c;
    const int cl_ = c >> 5;
    float s = 0.f;
    #pragma unroll 4
    for (int k = kh * 128; k < kh * 128 + 128; ++k)
        s = fmaf(cus[cl_][k], W[(size_t)k * NN + col], s);
    ps[kh][c] = s;
    __syncthreads();
    if (t < 128) {
        float sv = ps[0][t] + ps[1][t];
        float sq = sv * sv;
        sq += __shfl_xor(sq, 1);
        sq += __shfl_xor(sq, 2);
        sq += __shfl_xor(sq, 4);
        sq += __shfl_xor(sq, 8);
        sq += __shfl_xor(sq, 16);
        float inv = 1.f / sqrtf(sq + EPSQ);
        out[(size_t)b * NN + q * 128 + t] = sv * inv;
    }
}

extern "C" void kernel_launch(void* const* d_in, const int* in_sizes, int n_in,
                              void* d_out, int out_size, void* d_ws, size_t ws_size,
                              hipStream_t stream) {
    (void)in_sizes; (void)n_in; (void)out_size; (void)ws_size;
    const float* u = (const float*)d_in[0];
    const float* W = (const float*)d_in[1];

    float* ubar_part = (float*)d_ws;                           // 128*8*256
    float* v         = ubar_part + (size_t)B_SZ * NCH * KD;    // 128*512
    float* wv        = v + (size_t)B_SZ * NN;                  // 128*16*256
    float* cu_part   = wv + (size_t)B_SZ * NC * KD;            // 128*8*16*256 (~16 MB)

    reduce_u_k<<<1024, 256, 0, stream>>>(u, ubar_part);
    v0_k<<<512, 256, 0, stream>>>(ubar_part, W, v);

    wv_k<<<512, 256, 0, stream>>>(W, v, wv);
    fused_route_k<<<1024, 256, 0, stream>>>(u, wv, cu_part);
    sv_k<<<512, 256, 0, stream>>>(cu_part, W, v);

    wv_k<<<512, 256, 0, stream>>>(W, v, wv);
    fused_route_k<<<1024, 256, 0, stream>>>(u, wv, cu_part);
    sv_k<<<512, 256, 0, stream>>>(cu_part, W, (float*)d_out);
}